// Round 11
// baseline (336.415 us; speedup 1.0000x reference)
//
#include <hip/hip_runtime.h>

// LightGCN 2-layer propagation on MI355X — R20: R19 resubmitted verbatim
// after an infra-side container failure (3rd occurrence; R13's identical
// resubmit passed — kernel audit found no container-killing defect:
// bounds clamped, barriers block-uniform, LDS <= 38.2 KB, ws 40.7 MB,
// no runtime API in kernel_launch).
//
// Design (R19): slice-sorted entries for L2-resident gathers.
// R18 post-mortem: k_gat 67 us pinned at the fill wall — FETCH 207 MB
// (1.35x the 154 MB table-once-per-XCD floor), logical 512 MB at ~50% L2
// hit; PERM cut bank conflicts 18.4M -> 12.4M with NO time change =>
// conflicts off the critical path. R19/R20 makes table access temporally
// local: build sub-bins each bucket's entries by neighbor slice
// (slice = buck(nbr)>>7, 8 slices x 2.4 MB); k_gat processes cells in
// slice order, so all 1024 blocks sweep the table slice-by-slice and the
// instantaneous working set (~2.4-4.8 MB) fits per-XCD L2.
//   hist = [1024][8] = 32 KB LDS; CAPS = 640 = mean 488 + 6.9 sigma;
//   reservation = 8 padded cursors/thread (8192 addrs, ~300 chains).

#define NUM_USERS 100000
#define NUM_ITEMS 50000
#define N_NODES   150000
#define NUM_EDGES 2000000
#define EMB_D     64

#define BNODE  147                                 // nodes per bucket
#define NBUCK  1024                                // = build block size
#define MAGIC  29217465u                           // ceil(2^32/147), exact for n<72M
#define SL     8                                   // table slices (128 buckets each)
#define NCELL  (NBUCK * SL)                        // 8192 (bucket, slice) cells
#define E4     (NUM_EDGES / 4)                     // 500000 int4 per edge stream
#define PE     ((E4 + 1023) / 1024)                // 489 edge blocks
#define CAPS   640                                 // capacity per cell
#define CSTRIDE 16                                 // cursor padding (64 B)
#define CURN   (NCELL * CSTRIDE)                   // 131072 ints

#define ASTRIDE 65                                 // LDS acc row stride (ints)
#define ACCN    (BNODE * ASTRIDE)                  // 9555 ints = 38.2 KB
#define PERM(c) ((((c) & 7) << 3) | ((c) >> 3))    // bijective 0..63

#define CPYB   512                                 // concat blocks (1024 thr)
#define H8CNT  (N_NODES * (EMB_D / 8))             // 1.2M 16-byte chunks
#define UF4    (NUM_USERS * (EMB_D / 4))           // user float4 count

struct alignas(16) s8vec { short s[8]; };          // 8 int16 = 16 B

__device__ __forceinline__ unsigned buck(unsigned n) {
    return (unsigned)(((unsigned long long)n * MAGIC) >> 32);
}

__device__ __forceinline__ short q12(float x) {
    return (short)__float2int_rn(fminf(fmaxf(x * 4096.f, -32600.f), 32600.f));
}

// ---- 0) zero the reservation cursors ----
__global__ __launch_bounds__(1024) void k_zero(int* __restrict__ cur) {
    int i = blockIdx.x * 1024 + threadIdx.x;
    if (i < CURN) cur[i] = 0;
}

// ---- A) fused build: reg-resident histogram -> reserve -> scatter ----
// Entry for edge endpoint (dest r, neighbor c) goes to cell
// buck(r)*SL + (buck(c)>>7): bucket-major, neighbor-slice-minor.
__global__ __launch_bounds__(1024) void k_scatcat(const int* __restrict__ eidx,
                                                  int* __restrict__ cur,
                                                  unsigned* __restrict__ entries,
                                                  const float4* __restrict__ user4,
                                                  const float4* __restrict__ item4,
                                                  s8vec* __restrict__ tab) {
    int g = blockIdx.x, tid = threadIdx.x;
    if (g >= PE) {
        // concat: tab rows [0,NUM_USERS) = user, [NUM_USERS,N) = item (q12)
        int i = (g - PE) * 1024 + tid;
        const int stride = CPYB * 1024;
        for (; i < H8CNT; i += stride) {
            const float4* s = (i * 2 < UF4) ? (user4 + (size_t)i * 2)
                                            : (item4 + ((size_t)i * 2 - UF4));
            float4 a = s[0], b = s[1];
            s8vec o;
            o.s[0] = q12(a.x); o.s[1] = q12(a.y); o.s[2] = q12(a.z); o.s[3] = q12(a.w);
            o.s[4] = q12(b.x); o.s[5] = q12(b.y); o.s[6] = q12(b.z); o.s[7] = q12(b.w);
            tab[i] = o;
        }
        return;
    }

    __shared__ int lh[NCELL];                      // hist, then running cursor
    for (int i = tid; i < NCELL; i += 1024) lh[i] = 0;

    int j = g * 1024 + tid;                        // one int4-pair per thread
    bool act = j < E4;
    int rr[4] = {0, 0, 0, 0}, cc[4] = {0, 0, 0, 0};
    if (act) {
        int4 a = ((const int4*)eidx)[j];
        int4 b = ((const int4*)(eidx + NUM_EDGES))[j];
        rr[0] = a.x; rr[1] = a.y; rr[2] = a.z; rr[3] = a.w;
        cc[0] = b.x; cc[1] = b.y; cc[2] = b.z; cc[3] = b.w;
    }
    __syncthreads();

    // pass 1: histogram from registers
    if (act) {
        #pragma unroll
        for (int q = 0; q < 4; ++q) {
            unsigned br = buck((unsigned)rr[q]), bc = buck((unsigned)cc[q]);
            atomicAdd(&lh[br * SL + (bc >> 7)], 1);
            atomicAdd(&lh[bc * SL + (br >> 7)], 1);
        }
    }
    __syncthreads();

    // reserve: 8 cells per thread, one global atomic each
    for (int ci = tid; ci < NCELL; ci += 1024) {
        int h = lh[ci];
        int base = (h > 0) ? atomicAdd(&cur[ci * CSTRIDE], h) : 0;
        lh[ci] = base;
    }
    __syncthreads();

    // pass 2: scatter from the same registers (no edge re-read)
    if (act) {
        #pragma unroll
        for (int q = 0; q < 4; ++q) {
            unsigned r = (unsigned)rr[q], c = (unsigned)cc[q];
            unsigned br = buck(r), bc = buck(c);
            unsigned lr = r - br * BNODE, lc = c - bc * BNODE;
            int ci = (int)(br * SL + (bc >> 7));
            int p = atomicAdd(&lh[ci], 1);
            if (p < CAPS) entries[(size_t)ci * CAPS + p] = (lr << 18) | c;
            int ci2 = (int)(bc * SL + (br >> 7));
            int p2 = atomicAdd(&lh[ci2], 1);
            if (p2 < CAPS) entries[(size_t)ci2 * CAPS + p2] = (lc << 18) | r;
        }
    }
}

// ---- B) entry-centric bucket gather, slice-ordered ----
// Block = one bucket (147 nodes). Processes its 8 (bucket, slice) cells in
// slice order — all blocks sweep the table slice-by-slice, keeping the
// active slice (~2.4 MB) L2-resident. 8 lanes per entry: lane s loads
// 16 B (cols s*8..s*8+7, int16); ds_add into PERM'd accumulator.
// MODE 0: write inter16 (int16, scale 2^9). MODE 1: write fp32 out.
template <int MODE>
__global__ __launch_bounds__(512) void k_gat(const unsigned* __restrict__ entries,
                                             const int* __restrict__ cur,
                                             const s8vec* __restrict__ tv,
                                             void* __restrict__ dst) {
    __shared__ int acc[ACCN];                      // 38.2 KB
    int b = blockIdx.x, tid = threadIdx.x;

    for (int i = tid; i < ACCN; i += 512) acc[i] = 0;
    __syncthreads();

    int s = tid & 7;                               // col group 0..7
    int kk = tid >> 3;                             // entry slot 0..63

    for (int sc = 0; sc < SL; ++sc) {
        int ci = b * SL + sc;
        int cnt = min(cur[ci * CSTRIDE], CAPS);
        const unsigned* eb = entries + (size_t)ci * CAPS;

        int k = kk;
        if (k < cnt) {
            unsigned e = eb[k];
            s8vec r = tv[(size_t)(e & 0x3FFFFu) * 8 + s];
            for (k += 64; k < cnt; k += 64) {
                unsigned e2 = eb[k];               // prefetch next entry
                s8vec r2 = tv[(size_t)(e2 & 0x3FFFFu) * 8 + s];   // next row
                int cb = (int)(e >> 18) * ASTRIDE + s;
                atomicAdd(&acc[cb +  0], (int)r.s[0]);
                atomicAdd(&acc[cb +  8], (int)r.s[1]);
                atomicAdd(&acc[cb + 16], (int)r.s[2]);
                atomicAdd(&acc[cb + 24], (int)r.s[3]);
                atomicAdd(&acc[cb + 32], (int)r.s[4]);
                atomicAdd(&acc[cb + 40], (int)r.s[5]);
                atomicAdd(&acc[cb + 48], (int)r.s[6]);
                atomicAdd(&acc[cb + 56], (int)r.s[7]);
                e = e2; r = r2;
            }
            int cb = (int)(e >> 18) * ASTRIDE + s;
            atomicAdd(&acc[cb +  0], (int)r.s[0]);
            atomicAdd(&acc[cb +  8], (int)r.s[1]);
            atomicAdd(&acc[cb + 16], (int)r.s[2]);
            atomicAdd(&acc[cb + 24], (int)r.s[3]);
            atomicAdd(&acc[cb + 32], (int)r.s[4]);
            atomicAdd(&acc[cb + 40], (int)r.s[5]);
            atomicAdd(&acc[cb + 48], (int)r.s[6]);
            atomicAdd(&acc[cb + 56], (int)r.s[7]);
        }
    }
    __syncthreads();

    int nbase = b * BNODE;
    if constexpr (MODE == 0) {
        // inter16 = round(acc / 16): scale 2^9; pack 2 cols per int
        int* o = (int*)dst;
        for (int idx = tid; idx < BNODE * 32; idx += 512) {
            int loc = idx >> 5, cp = idx & 31;
            int node = nbase + loc;
            if (node < N_NODES) {
                int a0 = loc * ASTRIDE;
                int c0 = cp * 2, c1 = cp * 2 + 1;
                int v0 = (acc[a0 + PERM(c0)] + 8) >> 4;
                int v1 = (acc[a0 + PERM(c1)] + 8) >> 4;
                o[(size_t)node * 32 + cp] = (v0 & 0xFFFF) | (v1 << 16);
            }
        }
    } else {
        // out = acc * 0.5 / 2^9 = acc / 1024
        float* o = (float*)dst;
        for (int idx = tid; idx < BNODE * 64; idx += 512) {
            int loc = idx >> 6, col = idx & 63;
            int node = nbase + loc;
            if (node < N_NODES)
                o[(size_t)node * 64 + col] =
                    (float)acc[loc * ASTRIDE + PERM(col)] * (1.f / 1024.f);
        }
    }
}

extern "C" void kernel_launch(void* const* d_in, const int* in_sizes, int n_in,
                              void* d_out, int out_size, void* d_ws, size_t ws_size,
                              hipStream_t stream) {
    const int*   eidx = (const int*)d_in[0];     // [2, NUM_EDGES]
    const float* user = (const float*)d_in[1];   // [NUM_USERS, 64]
    const float* item = (const float*)d_in[2];   // [NUM_ITEMS, 64]
    float*       out  = (float*)d_out;           // [N_NODES, 64] fp32

    // int16 concat table lives in out[0 .. 19.2 MB) — dead once layer 2 writes.
    s8vec* tab16 = (s8vec*)out;

    char* ws = (char*)d_ws;
    size_t off = 0;
    auto alloc = [&](size_t bytes) {
        char* p = ws + off;
        off += (bytes + 255) & ~(size_t)255;
        return p;
    };
    unsigned* entries = (unsigned*)alloc((size_t)NCELL * CAPS * sizeof(unsigned)); // 21 MB
    s8vec*    inter16 = (s8vec*)alloc((size_t)N_NODES * 8 * sizeof(s8vec));        // 19.2 MB
    int*      cur     = (int*)alloc((size_t)CURN * sizeof(int));                   // 512 KB

    k_zero<<<(CURN + 1023) / 1024, 1024, 0, stream>>>(cur);
    k_scatcat<<<PE + CPYB, 1024, 0, stream>>>(eidx, cur, entries,
                                              (const float4*)user,
                                              (const float4*)item, tab16);
    k_gat<0><<<NBUCK, 512, 0, stream>>>(entries, cur, tab16, inter16);
    k_gat<1><<<NBUCK, 512, 0, stream>>>(entries, cur, inter16, out);
}

// Round 12
// 253.797 us; speedup vs baseline: 1.3255x; 1.3255x over previous
//
#include <hip/hip_runtime.h>

// LightGCN 2-layer propagation on MI355X — R21: R18 architecture (best,
// 269 us) + coarse-chunk build to kill scatter-write amplification.
//
// R20 post-mortem: slice binning rejected — gather FETCH floor is
// ~175 MB (table-once-per-XCD 154 + entries 21) vs 207 measured, only
// 15% headroom; and 8192-cell binning made build writes ~1 entry/cell
// -> full 64B-line amplification (WRITE 137->225 MB, scatcat 73->151 us).
// R21 reverts to single-level bucket binning and enlarges per-block
// chunks instead: 128 edge blocks x 1024 thr x 4 int4-pairs/thread
// (reg-resident, statically indexed) -> ~32 entries = 128 B = 2 full
// lines per (block, bucket) chunk -> amplification ~1.25x; reservation
// chains 489->128. Concat blocks (512) backfill CUs during edge phase.
// k_gat verbatim from R18 (near fill floor; PERM retained).

#define NUM_USERS 100000
#define NUM_ITEMS 50000
#define N_NODES   150000
#define NUM_EDGES 2000000
#define EMB_D     64

#define BNODE  147                                 // nodes per bucket
#define NBUCK  1024                                // buckets (= hist bins)
#define MAGIC  29217465u                           // ceil(2^32/147), exact for n<72M
#define E4     (NUM_EDGES / 4)                     // 500000 int4 per edge stream
#define PE     128                                 // edge blocks
#define QPT    4                                   // int4-pairs per thread
#define CAP    5120                                // bucket region capacity
#define CSTRIDE 16                                 // cursor padding (64 B)
#define CURN   (NBUCK * CSTRIDE)                   // 16384 ints

#define ASTRIDE 65                                 // LDS acc row stride (ints)
#define ACCN    (BNODE * ASTRIDE)                  // 9555 ints = 38.2 KB
#define PERM(c) ((((c) & 7) << 3) | ((c) >> 3))    // bijective 0..63

#define CPYB   512                                 // concat blocks (1024 thr)
#define H8CNT  (N_NODES * (EMB_D / 8))             // 1.2M 16-byte chunks
#define UF4    (NUM_USERS * (EMB_D / 4))           // user float4 count

struct alignas(16) s8vec { short s[8]; };          // 8 int16 = 16 B

__device__ __forceinline__ unsigned buck(unsigned n) {
    return (unsigned)(((unsigned long long)n * MAGIC) >> 32);
}

__device__ __forceinline__ short q12(float x) {
    return (short)__float2int_rn(fminf(fmaxf(x * 4096.f, -32600.f), 32600.f));
}

// ---- 0) zero the reservation cursors ----
__global__ __launch_bounds__(1024) void k_zero(int* __restrict__ cur) {
    int i = blockIdx.x * 1024 + threadIdx.x;
    if (i < CURN) cur[i] = 0;
}

// ---- A) fused build: reg-resident histogram -> reserve -> scatter ----
// Each edge thread owns 4 int4-pairs (16 edges, 32 endpoints) in regs.
__global__ __launch_bounds__(1024) void k_scatcat(const int* __restrict__ eidx,
                                                  int* __restrict__ cur,
                                                  unsigned* __restrict__ entries,
                                                  const float4* __restrict__ user4,
                                                  const float4* __restrict__ item4,
                                                  s8vec* __restrict__ tab) {
    int g = blockIdx.x, tid = threadIdx.x;
    if (g >= PE) {
        // concat: tab rows [0,NUM_USERS) = user, [NUM_USERS,N) = item (q12)
        int i = (g - PE) * 1024 + tid;
        const int stride = CPYB * 1024;
        for (; i < H8CNT; i += stride) {
            const float4* s = (i * 2 < UF4) ? (user4 + (size_t)i * 2)
                                            : (item4 + ((size_t)i * 2 - UF4));
            float4 a = s[0], b = s[1];
            s8vec o;
            o.s[0] = q12(a.x); o.s[1] = q12(a.y); o.s[2] = q12(a.z); o.s[3] = q12(a.w);
            o.s[4] = q12(b.x); o.s[5] = q12(b.y); o.s[6] = q12(b.z); o.s[7] = q12(b.w);
            tab[i] = o;
        }
        return;
    }

    __shared__ int lh[NBUCK];                      // hist, then running cursor
    lh[tid] = 0;                                   // 1024 threads == NBUCK

    const int4* r4 = (const int4*)eidx;
    const int4* c4 = (const int4*)(eidx + NUM_EDGES);
    int rr[4 * QPT], cc[4 * QPT];
    bool actq[QPT];
    #pragma unroll
    for (int q = 0; q < QPT; ++q) {
        int j = g * (1024 * QPT) + q * 1024 + tid;
        actq[q] = (j < E4);
        if (actq[q]) {
            int4 a = r4[j], b = c4[j];
            rr[q * 4 + 0] = a.x; rr[q * 4 + 1] = a.y;
            rr[q * 4 + 2] = a.z; rr[q * 4 + 3] = a.w;
            cc[q * 4 + 0] = b.x; cc[q * 4 + 1] = b.y;
            cc[q * 4 + 2] = b.z; cc[q * 4 + 3] = b.w;
        } else {
            rr[q * 4 + 0] = rr[q * 4 + 1] = rr[q * 4 + 2] = rr[q * 4 + 3] = 0;
            cc[q * 4 + 0] = cc[q * 4 + 1] = cc[q * 4 + 2] = cc[q * 4 + 3] = 0;
        }
    }
    __syncthreads();

    // pass 1: histogram from registers
    #pragma unroll
    for (int q = 0; q < QPT; ++q) {
        if (actq[q]) {
            #pragma unroll
            for (int t = 0; t < 4; ++t) {
                atomicAdd(&lh[buck((unsigned)rr[q * 4 + t])], 1);
                atomicAdd(&lh[buck((unsigned)cc[q * 4 + t])], 1);
            }
        }
    }
    __syncthreads();

    // reserve: one bucket per thread, single global atomic
    {
        int h = lh[tid];
        int base = (h > 0) ? atomicAdd(&cur[tid * CSTRIDE], h) : 0;
        lh[tid] = base;
    }
    __syncthreads();

    // pass 2: scatter from the same registers (no edge re-read)
    #pragma unroll
    for (int q = 0; q < QPT; ++q) {
        if (actq[q]) {
            #pragma unroll
            for (int t = 0; t < 4; ++t) {
                unsigned r = (unsigned)rr[q * 4 + t], c = (unsigned)cc[q * 4 + t];
                unsigned br = buck(r), bc = buck(c);
                unsigned lr = r - br * BNODE, lc = c - bc * BNODE;
                int p = atomicAdd(&lh[br], 1);
                if (p < CAP) entries[(size_t)br * CAP + p] = (lr << 18) | c;
                int p2 = atomicAdd(&lh[bc], 1);
                if (p2 < CAP) entries[(size_t)bc * CAP + p2] = (lc << 18) | r;
            }
        }
    }
}

// ---- B) entry-centric bucket gather, int32 LDS accumulation ----
// Block = one bucket (147 nodes). 8 lanes per entry: lane s loads 16 B
// (cols s*8..s*8+7, int16) of the neighbor's row; ds_add into permuted
// accumulator layout: col c of node loc lives at loc*ASTRIDE + PERM(c).
// 1-deep software pipeline on (entry, row).
// MODE 0: write inter16 (int16, scale 2^9). MODE 1: write fp32 out.
template <int MODE>
__global__ __launch_bounds__(512) void k_gat(const unsigned* __restrict__ entries,
                                             const int* __restrict__ cur,
                                             const s8vec* __restrict__ tv,
                                             void* __restrict__ dst) {
    __shared__ int acc[ACCN];                      // 38.2 KB
    int b = blockIdx.x, tid = threadIdx.x;

    for (int i = tid; i < ACCN; i += 512) acc[i] = 0;

    int cnt = min(cur[b * CSTRIDE], CAP);
    const unsigned* eb = entries + (size_t)b * CAP;
    __syncthreads();

    int s = tid & 7;                               // col group 0..7
    int kk = tid >> 3;                             // entry slot 0..63

    int k = kk;
    if (k < cnt) {
        unsigned e = eb[k];
        s8vec r = tv[(size_t)(e & 0x3FFFFu) * 8 + s];
        for (k += 64; k < cnt; k += 64) {
            unsigned e2 = eb[k];                   // prefetch next entry
            s8vec r2 = tv[(size_t)(e2 & 0x3FFFFu) * 8 + s];   // next row
            int cb = (int)(e >> 18) * ASTRIDE + s;
            atomicAdd(&acc[cb +  0], (int)r.s[0]);
            atomicAdd(&acc[cb +  8], (int)r.s[1]);
            atomicAdd(&acc[cb + 16], (int)r.s[2]);
            atomicAdd(&acc[cb + 24], (int)r.s[3]);
            atomicAdd(&acc[cb + 32], (int)r.s[4]);
            atomicAdd(&acc[cb + 40], (int)r.s[5]);
            atomicAdd(&acc[cb + 48], (int)r.s[6]);
            atomicAdd(&acc[cb + 56], (int)r.s[7]);
            e = e2; r = r2;
        }
        int cb = (int)(e >> 18) * ASTRIDE + s;
        atomicAdd(&acc[cb +  0], (int)r.s[0]);
        atomicAdd(&acc[cb +  8], (int)r.s[1]);
        atomicAdd(&acc[cb + 16], (int)r.s[2]);
        atomicAdd(&acc[cb + 24], (int)r.s[3]);
        atomicAdd(&acc[cb + 32], (int)r.s[4]);
        atomicAdd(&acc[cb + 40], (int)r.s[5]);
        atomicAdd(&acc[cb + 48], (int)r.s[6]);
        atomicAdd(&acc[cb + 56], (int)r.s[7]);
    }
    __syncthreads();

    int nbase = b * BNODE;
    if constexpr (MODE == 0) {
        // inter16 = round(acc / 16): scale 2^9; pack 2 cols per int
        int* o = (int*)dst;
        for (int idx = tid; idx < BNODE * 32; idx += 512) {
            int loc = idx >> 5, cp = idx & 31;
            int node = nbase + loc;
            if (node < N_NODES) {
                int a0 = loc * ASTRIDE;
                int c0 = cp * 2, c1 = cp * 2 + 1;
                int v0 = (acc[a0 + PERM(c0)] + 8) >> 4;
                int v1 = (acc[a0 + PERM(c1)] + 8) >> 4;
                o[(size_t)node * 32 + cp] = (v0 & 0xFFFF) | (v1 << 16);
            }
        }
    } else {
        // out = acc * 0.5 / 2^9 = acc / 1024
        float* o = (float*)dst;
        for (int idx = tid; idx < BNODE * 64; idx += 512) {
            int loc = idx >> 6, col = idx & 63;
            int node = nbase + loc;
            if (node < N_NODES)
                o[(size_t)node * 64 + col] =
                    (float)acc[loc * ASTRIDE + PERM(col)] * (1.f / 1024.f);
        }
    }
}

extern "C" void kernel_launch(void* const* d_in, const int* in_sizes, int n_in,
                              void* d_out, int out_size, void* d_ws, size_t ws_size,
                              hipStream_t stream) {
    const int*   eidx = (const int*)d_in[0];     // [2, NUM_EDGES]
    const float* user = (const float*)d_in[1];   // [NUM_USERS, 64]
    const float* item = (const float*)d_in[2];   // [NUM_ITEMS, 64]
    float*       out  = (float*)d_out;           // [N_NODES, 64] fp32

    // int16 concat table lives in out[0 .. 19.2 MB) — dead once layer 2 writes.
    s8vec* tab16 = (s8vec*)out;

    char* ws = (char*)d_ws;
    size_t off = 0;
    auto alloc = [&](size_t bytes) {
        char* p = ws + off;
        off += (bytes + 255) & ~(size_t)255;
        return p;
    };
    unsigned* entries = (unsigned*)alloc((size_t)NBUCK * CAP * sizeof(unsigned));   // 21 MB
    s8vec*    inter16 = (s8vec*)alloc((size_t)N_NODES * 8 * sizeof(s8vec));         // 19.2 MB
    int*      cur     = (int*)alloc((size_t)CURN * sizeof(int));                    // 64 KB

    k_zero<<<(CURN + 1023) / 1024, 1024, 0, stream>>>(cur);
    k_scatcat<<<PE + CPYB, 1024, 0, stream>>>(eidx, cur, entries,
                                              (const float4*)user,
                                              (const float4*)item, tab16);
    k_gat<0><<<NBUCK, 512, 0, stream>>>(entries, cur, tab16, inter16);
    k_gat<1><<<NBUCK, 512, 0, stream>>>(entries, cur, inter16, out);
}